// Round 2
// baseline (60.089 us; speedup 1.0000x reference)
//
#include <hip/hip_runtime.h>
#include <hip/hip_bf16.h>

#define IN_DIM  8192
#define OUT_DIM 16384
#define BATCH   2048
#define NG      16

// ---------------------------------------------------------------------------
// The 16-gate mixture is linear in {a*b, a, b, 1}. Per output column j,
// softmax(logits[j]) collapses to 4 coefficients:
//   out = w_ab*(a*b) + w_a*a + w_b*b + w_c
// ---------------------------------------------------------------------------

__device__ __forceinline__ float4 collapse_weights(const float* __restrict__ l) {
    float v[NG];
    float m = -1e30f;
#pragma unroll
    for (int k = 0; k < NG; ++k) { v[k] = l[k]; m = fmaxf(m, v[k]); }
    float s = 0.f;
#pragma unroll
    for (int k = 0; k < NG; ++k) { v[k] = __expf(v[k] - m); s += v[k]; }
    float inv = 1.0f / s;
#pragma unroll
    for (int k = 0; k < NG; ++k) v[k] *= inv;
    float w_ab = v[1] - v[2] - v[4] - 2.f * v[6] - v[7] + v[8] + 2.f * v[9]
               + v[11] + v[13] - v[14];
    float w_a  = v[2] + v[3] + v[6] + v[7] - v[8] - v[9] - v[12] - v[13];
    float w_b  = v[4] + v[5] + v[6] + v[7] - v[8] - v[9] - v[10] - v[11];
    float w_c  = v[8] + v[9] + v[10] + v[11] + v[12] + v[13] + v[14] + v[15];
    return make_float4(w_ab, w_a, w_b, w_c);
}

// Kernel 1: one softmax per output column -> 4 coefficients into d_ws.
__global__ __launch_bounds__(256) void gate_weights_kernel(
    const float* __restrict__ logits, float4* __restrict__ w) {
    int j = blockIdx.x * blockDim.x + threadIdx.x;
    if (j >= OUT_DIM) return;
    w[j] = collapse_weights(logits + (size_t)j * NG);
}

// Kernel 2: one block per batch row. Stage the 32 KB x-row in LDS, then each
// thread computes 4 consecutive columns per iter: int4 idx loads, 8 LDS
// gathers, 4x float4 weight loads (L2-resident), float4 store.
__global__ __launch_bounds__(256) void gate_eval_kernel(
    const float* __restrict__ x,
    const float4* __restrict__ w,
    const int4* __restrict__ a_idx,
    const int4* __restrict__ b_idx,
    float4* __restrict__ out) {
    __shared__ float row[IN_DIM];
    const int i = blockIdx.x;

    const float4* xr = (const float4*)(x + (size_t)i * IN_DIM);
    float4* rv = (float4*)row;
#pragma unroll
    for (int t = 0; t < IN_DIM / 4 / 256; ++t)
        rv[threadIdx.x + t * 256] = xr[threadIdx.x + t * 256];
    __syncthreads();

    float4* o = out + (size_t)i * (OUT_DIM / 4);
#pragma unroll 4
    for (int k = 0; k < OUT_DIM / 4 / 256; ++k) {
        int j4 = threadIdx.x + k * 256;
        int4 ai = a_idx[j4];
        int4 bi = b_idx[j4];
        float4 r;
        {
            float a = row[ai.x], b = row[bi.x];
            float4 ww = w[j4 * 4 + 0];
            r.x = fmaf(ww.x, a * b, fmaf(ww.y, a, fmaf(ww.z, b, ww.w)));
        }
        {
            float a = row[ai.y], b = row[bi.y];
            float4 ww = w[j4 * 4 + 1];
            r.y = fmaf(ww.x, a * b, fmaf(ww.y, a, fmaf(ww.z, b, ww.w)));
        }
        {
            float a = row[ai.z], b = row[bi.z];
            float4 ww = w[j4 * 4 + 2];
            r.z = fmaf(ww.x, a * b, fmaf(ww.y, a, fmaf(ww.z, b, ww.w)));
        }
        {
            float a = row[ai.w], b = row[bi.w];
            float4 ww = w[j4 * 4 + 3];
            r.w = fmaf(ww.x, a * b, fmaf(ww.y, a, fmaf(ww.z, b, ww.w)));
        }
        o[j4] = r;
    }
}

// Fallback (only if ws_size < 256 KB): recompute softmax inline per column.
// Slow but correct; never taken if the harness gives us real scratch.
__global__ __launch_bounds__(256) void gate_eval_fused_kernel(
    const float* __restrict__ x,
    const float* __restrict__ logits,
    const int* __restrict__ a_idx,
    const int* __restrict__ b_idx,
    float* __restrict__ out) {
    __shared__ float row[IN_DIM];
    const int i = blockIdx.x;
    const float4* xr = (const float4*)(x + (size_t)i * IN_DIM);
    float4* rv = (float4*)row;
#pragma unroll
    for (int t = 0; t < IN_DIM / 4 / 256; ++t)
        rv[threadIdx.x + t * 256] = xr[threadIdx.x + t * 256];
    __syncthreads();
    float* o = out + (size_t)i * OUT_DIM;
    for (int k = 0; k < OUT_DIM / 256; ++k) {
        int j = threadIdx.x + k * 256;
        float4 ww = collapse_weights(logits + (size_t)j * NG);
        float a = row[a_idx[j]], b = row[b_idx[j]];
        o[j] = fmaf(ww.x, a * b, fmaf(ww.y, a, fmaf(ww.z, b, ww.w)));
    }
}

extern "C" void kernel_launch(void* const* d_in, const int* in_sizes, int n_in,
                              void* d_out, int out_size, void* d_ws, size_t ws_size,
                              hipStream_t stream) {
    const float* x      = (const float*)d_in[0];
    const float* logits = (const float*)d_in[1];
    const int*   a_idx  = (const int*)d_in[2];
    const int*   b_idx  = (const int*)d_in[3];
    float* out = (float*)d_out;

    if (ws_size >= (size_t)OUT_DIM * sizeof(float4) && d_ws != nullptr) {
        float4* w = (float4*)d_ws;  // 16384 * 16 B = 256 KB
        gate_weights_kernel<<<OUT_DIM / 256, 256, 0, stream>>>(logits, w);
        gate_eval_kernel<<<BATCH, 256, 0, stream>>>(
            x, w, (const int4*)a_idx, (const int4*)b_idx, (float4*)out);
    } else {
        gate_eval_fused_kernel<<<BATCH, 256, 0, stream>>>(
            x, logits, a_idx, b_idx, out);
    }
}

// Round 4
// 59.706 us; speedup vs baseline: 1.0064x; 1.0064x over previous
//
#include <hip/hip_runtime.h>
#include <hip/hip_bf16.h>

#define IN_DIM  8192
#define OUT_DIM 16384
#define BATCH   2048
#define NG      16
#define CHUNKS  2   // column-chunks per row

typedef float f32x4 __attribute__((ext_vector_type(4)));
typedef int   i32x4 __attribute__((ext_vector_type(4)));

// ---------------------------------------------------------------------------
// The 16-gate mixture is linear in {a*b, a, b, 1}: per column j,
//   out = w_ab*(a*b) + w_a*a + w_b*b + w_c, with w_* from softmax(logits[j]).
// Weights stored SoA so eval-kernel loads coalesce.
// ---------------------------------------------------------------------------

__device__ __forceinline__ void collapse_weights(const float* __restrict__ l,
                                                 float& w_ab, float& w_a,
                                                 float& w_b, float& w_c) {
    float v[NG];
    float m = -1e30f;
#pragma unroll
    for (int k = 0; k < NG; ++k) { v[k] = l[k]; m = fmaxf(m, v[k]); }
    float s = 0.f;
#pragma unroll
    for (int k = 0; k < NG; ++k) { v[k] = __expf(v[k] - m); s += v[k]; }
    float inv = 1.0f / s;
#pragma unroll
    for (int k = 0; k < NG; ++k) v[k] *= inv;
    w_ab = v[1] - v[2] - v[4] - 2.f * v[6] - v[7] + v[8] + 2.f * v[9]
         + v[11] + v[13] - v[14];
    w_a  = v[2] + v[3] + v[6] + v[7] - v[8] - v[9] - v[12] - v[13];
    w_b  = v[4] + v[5] + v[6] + v[7] - v[8] - v[9] - v[10] - v[11];
    w_c  = v[8] + v[9] + v[10] + v[11] + v[12] + v[13] + v[14] + v[15];
}

// Kernel 1: per-column softmax -> 4 SoA coefficient arrays in d_ws.
__global__ __launch_bounds__(256) void gate_weights_kernel(
    const float* __restrict__ logits, float* __restrict__ ws) {
    int j = blockIdx.x * blockDim.x + threadIdx.x;
    if (j >= OUT_DIM) return;
    float w_ab, w_a, w_b, w_c;
    collapse_weights(logits + (size_t)j * NG, w_ab, w_a, w_b, w_c);
    ws[j]               = w_ab;
    ws[j +     OUT_DIM] = w_a;
    ws[j + 2 * OUT_DIM] = w_b;
    ws[j + 3 * OUT_DIM] = w_c;
}

// Kernel 2: grid = BATCH*CHUNKS. Each block stages its row (32 KB LDS), then
// computes OUT_DIM/CHUNKS columns: all table loads coalesced float4/int4,
// 8 random LDS gathers, non-temporal float4 store.
__global__ __launch_bounds__(256) void gate_eval_kernel(
    const float* __restrict__ x,
    const float* __restrict__ ws,
    const i32x4* __restrict__ a_idx4,
    const i32x4* __restrict__ b_idx4,
    f32x4* __restrict__ out4) {
    __shared__ float row[IN_DIM];
    const int bid   = blockIdx.x;
    const int i     = bid >> 1;          // batch row (CHUNKS == 2)
    const int chunk = bid & 1;

    const f32x4* xr = (const f32x4*)(x + (size_t)i * IN_DIM);
    f32x4* rv = (f32x4*)row;
#pragma unroll
    for (int t = 0; t < IN_DIM / 4 / 256; ++t)
        rv[threadIdx.x + t * 256] = xr[threadIdx.x + t * 256];
    __syncthreads();

    const f32x4* wab4 = (const f32x4*)(ws);
    const f32x4* wa4  = (const f32x4*)(ws + OUT_DIM);
    const f32x4* wb4  = (const f32x4*)(ws + 2 * OUT_DIM);
    const f32x4* wc4  = (const f32x4*)(ws + 3 * OUT_DIM);

    const int base4 = chunk * (OUT_DIM / CHUNKS / 4);
    f32x4* o4 = out4 + (size_t)i * (OUT_DIM / 4);

#pragma unroll 4
    for (int k = 0; k < OUT_DIM / CHUNKS / 4 / 256; ++k) {
        int j4 = base4 + threadIdx.x + k * 256;
        i32x4 ai = a_idx4[j4];
        i32x4 bi = b_idx4[j4];
        f32x4 wab = wab4[j4], wa = wa4[j4], wb = wb4[j4], wc = wc4[j4];
        f32x4 r;
#pragma unroll
        for (int c = 0; c < 4; ++c) {
            float a = row[ai[c]], b = row[bi[c]];
            r[c] = fmaf(wab[c], a * b, fmaf(wa[c], a, fmaf(wb[c], b, wc[c])));
        }
        __builtin_nontemporal_store(r, &o4[j4]);
    }
}

// Fallback if ws_size is too small: recompute softmax inline per column.
__global__ __launch_bounds__(256) void gate_eval_fused_kernel(
    const float* __restrict__ x,
    const float* __restrict__ logits,
    const int* __restrict__ a_idx,
    const int* __restrict__ b_idx,
    float* __restrict__ out) {
    __shared__ float row[IN_DIM];
    const int i = blockIdx.x;
    const f32x4* xr = (const f32x4*)(x + (size_t)i * IN_DIM);
    f32x4* rv = (f32x4*)row;
#pragma unroll
    for (int t = 0; t < IN_DIM / 4 / 256; ++t)
        rv[threadIdx.x + t * 256] = xr[threadIdx.x + t * 256];
    __syncthreads();
    float* o = out + (size_t)i * OUT_DIM;
    for (int k = 0; k < OUT_DIM / 256; ++k) {
        int j = threadIdx.x + k * 256;
        float w_ab, w_a, w_b, w_c;
        collapse_weights(logits + (size_t)j * NG, w_ab, w_a, w_b, w_c);
        float a = row[a_idx[j]], b = row[b_idx[j]];
        o[j] = fmaf(w_ab, a * b, fmaf(w_a, a, fmaf(w_b, b, w_c)));
    }
}

extern "C" void kernel_launch(void* const* d_in, const int* in_sizes, int n_in,
                              void* d_out, int out_size, void* d_ws, size_t ws_size,
                              hipStream_t stream) {
    const float* x      = (const float*)d_in[0];
    const float* logits = (const float*)d_in[1];
    const int*   a_idx  = (const int*)d_in[2];
    const int*   b_idx  = (const int*)d_in[3];
    float* out = (float*)d_out;

    if (ws_size >= (size_t)4 * OUT_DIM * sizeof(float) && d_ws != nullptr) {
        float* ws = (float*)d_ws;  // 4 * 16384 * 4 B = 256 KB, SoA
        gate_weights_kernel<<<OUT_DIM / 256, 256, 0, stream>>>(logits, ws);
        gate_eval_kernel<<<BATCH * CHUNKS, 256, 0, stream>>>(
            x, ws, (const i32x4*)a_idx, (const i32x4*)b_idx, (f32x4*)out);
    } else {
        gate_eval_fused_kernel<<<BATCH, 256, 0, stream>>>(
            x, logits, a_idx, b_idx, out);
    }
}

// Round 5
// 50.910 us; speedup vs baseline: 1.1803x; 1.1728x over previous
//
#include <hip/hip_runtime.h>
#include <hip/hip_bf16.h>

#define IN_DIM  8192
#define OUT_DIM 16384
#define BATCH   2048
#define NG      16
#define CHUNKS  2     // column-chunks per row
#define TPB     512   // 8 waves/block; 4 blocks/CU -> 32 waves/CU (100%)

typedef float        f32x4 __attribute__((ext_vector_type(4)));
typedef unsigned int u32x4 __attribute__((ext_vector_type(4)));

// ---------------------------------------------------------------------------
// The 16-gate mixture is linear in {a*b, a, b, 1}: per column j,
//   out = w_ab*(a*b) + w_a*a + w_b*b + w_c, with w_* from softmax(logits[j]).
// ws layout (SoA): [w_ab | w_a | w_b | w_c] (4*OUT_DIM f32) then packed
// indices (OUT_DIM u32: a_idx | b_idx<<16).
// ---------------------------------------------------------------------------

__device__ __forceinline__ void collapse_weights(const float* __restrict__ l,
                                                 float& w_ab, float& w_a,
                                                 float& w_b, float& w_c) {
    float v[NG];
    float m = -1e30f;
#pragma unroll
    for (int k = 0; k < NG; ++k) { v[k] = l[k]; m = fmaxf(m, v[k]); }
    float s = 0.f;
#pragma unroll
    for (int k = 0; k < NG; ++k) { v[k] = __expf(v[k] - m); s += v[k]; }
    float inv = 1.0f / s;
#pragma unroll
    for (int k = 0; k < NG; ++k) v[k] *= inv;
    w_ab = v[1] - v[2] - v[4] - 2.f * v[6] - v[7] + v[8] + 2.f * v[9]
         + v[11] + v[13] - v[14];
    w_a  = v[2] + v[3] + v[6] + v[7] - v[8] - v[9] - v[12] - v[13];
    w_b  = v[4] + v[5] + v[6] + v[7] - v[8] - v[9] - v[10] - v[11];
    w_c  = v[8] + v[9] + v[10] + v[11] + v[12] + v[13] + v[14] + v[15];
}

// Kernel 1: per-column softmax -> SoA coefficients + packed u16 index pairs.
__global__ __launch_bounds__(256) void gate_weights_kernel(
    const float* __restrict__ logits,
    const int* __restrict__ a_idx, const int* __restrict__ b_idx,
    float* __restrict__ ws) {
    int j = blockIdx.x * blockDim.x + threadIdx.x;
    if (j >= OUT_DIM) return;
    float w_ab, w_a, w_b, w_c;
    collapse_weights(logits + (size_t)j * NG, w_ab, w_a, w_b, w_c);
    ws[j]               = w_ab;
    ws[j +     OUT_DIM] = w_a;
    ws[j + 2 * OUT_DIM] = w_b;
    ws[j + 3 * OUT_DIM] = w_c;
    unsigned int* pk = (unsigned int*)(ws + 4 * OUT_DIM);
    pk[j] = (unsigned int)a_idx[j] | ((unsigned int)b_idx[j] << 16);
}

// Kernel 2: grid = BATCH*CHUNKS, 512 threads. Stage the 32 KB fp32 row in LDS
// (shared by 8 waves), then 4 iters: packed-idx u32x4 load, 4 SoA weight
// f32x4 loads, 8 random LDS gathers, non-temporal f32x4 store.
__global__ __launch_bounds__(TPB, 8) void gate_eval_kernel(
    const float* __restrict__ x,
    const float* __restrict__ ws,
    f32x4* __restrict__ out4) {
    __shared__ float row[IN_DIM];
    const int bid   = blockIdx.x;
    const int i     = bid >> 1;          // batch row (CHUNKS == 2)
    const int chunk = bid & 1;

    const f32x4* xr = (const f32x4*)(x + (size_t)i * IN_DIM);
    f32x4* rv = (f32x4*)row;
#pragma unroll
    for (int t = 0; t < IN_DIM / 4 / TPB; ++t)   // 4 iters
        rv[threadIdx.x + t * TPB] = xr[threadIdx.x + t * TPB];
    __syncthreads();

    const f32x4* wab4 = (const f32x4*)(ws);
    const f32x4* wa4  = (const f32x4*)(ws + OUT_DIM);
    const f32x4* wb4  = (const f32x4*)(ws + 2 * OUT_DIM);
    const f32x4* wc4  = (const f32x4*)(ws + 3 * OUT_DIM);
    const u32x4* pk4  = (const u32x4*)(ws + 4 * OUT_DIM);

    const int base4 = chunk * (OUT_DIM / CHUNKS / 4);
    f32x4* o4 = out4 + (size_t)i * (OUT_DIM / 4);

#pragma unroll 2
    for (int k = 0; k < OUT_DIM / CHUNKS / 4 / TPB; ++k) {  // 4 iters
        int j4 = base4 + threadIdx.x + k * TPB;
        u32x4 pk = pk4[j4];
        f32x4 wab = wab4[j4], wa = wa4[j4], wb = wb4[j4], wc = wc4[j4];
        f32x4 r;
#pragma unroll
        for (int c = 0; c < 4; ++c) {
            float a = row[pk[c] & 0xFFFFu];
            float b = row[pk[c] >> 16];
            r[c] = fmaf(wab[c], a * b, fmaf(wa[c], a, fmaf(wb[c], b, wc[c])));
        }
        __builtin_nontemporal_store(r, &o4[j4]);
    }
}

// Fallback if ws_size is too small: recompute softmax inline per column.
__global__ __launch_bounds__(256) void gate_eval_fused_kernel(
    const float* __restrict__ x,
    const float* __restrict__ logits,
    const int* __restrict__ a_idx,
    const int* __restrict__ b_idx,
    float* __restrict__ out) {
    __shared__ float row[IN_DIM];
    const int i = blockIdx.x;
    const f32x4* xr = (const f32x4*)(x + (size_t)i * IN_DIM);
    f32x4* rv = (f32x4*)row;
#pragma unroll
    for (int t = 0; t < IN_DIM / 4 / 256; ++t)
        rv[threadIdx.x + t * 256] = xr[threadIdx.x + t * 256];
    __syncthreads();
    float* o = out + (size_t)i * OUT_DIM;
    for (int k = 0; k < OUT_DIM / 256; ++k) {
        int j = threadIdx.x + k * 256;
        float w_ab, w_a, w_b, w_c;
        collapse_weights(logits + (size_t)j * NG, w_ab, w_a, w_b, w_c);
        float a = row[a_idx[j]], b = row[b_idx[j]];
        o[j] = fmaf(w_ab, a * b, fmaf(w_a, a, fmaf(w_b, b, w_c)));
    }
}

extern "C" void kernel_launch(void* const* d_in, const int* in_sizes, int n_in,
                              void* d_out, int out_size, void* d_ws, size_t ws_size,
                              hipStream_t stream) {
    const float* x      = (const float*)d_in[0];
    const float* logits = (const float*)d_in[1];
    const int*   a_idx  = (const int*)d_in[2];
    const int*   b_idx  = (const int*)d_in[3];
    float* out = (float*)d_out;

    const size_t ws_need = (size_t)(4 * OUT_DIM) * sizeof(float)
                         + (size_t)OUT_DIM * sizeof(unsigned int);  // 320 KB
    if (ws_size >= ws_need && d_ws != nullptr) {
        float* ws = (float*)d_ws;
        gate_weights_kernel<<<OUT_DIM / 256, 256, 0, stream>>>(
            logits, a_idx, b_idx, ws);
        gate_eval_kernel<<<BATCH * CHUNKS, TPB, 0, stream>>>(
            x, ws, (f32x4*)out);
    } else {
        gate_eval_fused_kernel<<<BATCH, 256, 0, stream>>>(
            x, logits, a_idx, b_idx, out);
    }
}

// Round 6
// 50.222 us; speedup vs baseline: 1.1965x; 1.0137x over previous
//
#include <hip/hip_runtime.h>
#include <hip/hip_bf16.h>

#define IN_DIM  8192
#define OUT_DIM 16384
#define BATCH   2048
#define NG      16
#define CHUNKS  2     // column-chunks per row-pair
#define RROWS   2     // batch rows per block (table amortization)
#define TPB     512

typedef float        f32x4 __attribute__((ext_vector_type(4)));
typedef unsigned int u32x4 __attribute__((ext_vector_type(4)));

// ---------------------------------------------------------------------------
// Gate mixture is linear in {a*b, a, b, 1}: out = w_ab*ab + w_a*a + w_b*b + w_c.
// ws layout (SoA): [w_ab | w_a | w_b | w_c] (4*OUT_DIM f32), then packed
// indices (OUT_DIM u32: a_idx | b_idx<<16).
// Eval: 2 rows per block share each 20 B/column table read (L2-stream halved).
// ---------------------------------------------------------------------------

__device__ __forceinline__ void collapse_weights(const float* __restrict__ l,
                                                 float& w_ab, float& w_a,
                                                 float& w_b, float& w_c) {
    float v[NG];
    float m = -1e30f;
#pragma unroll
    for (int k = 0; k < NG; ++k) { v[k] = l[k]; m = fmaxf(m, v[k]); }
    float s = 0.f;
#pragma unroll
    for (int k = 0; k < NG; ++k) { v[k] = __expf(v[k] - m); s += v[k]; }
    float inv = 1.0f / s;
#pragma unroll
    for (int k = 0; k < NG; ++k) v[k] *= inv;
    w_ab = v[1] - v[2] - v[4] - 2.f * v[6] - v[7] + v[8] + 2.f * v[9]
         + v[11] + v[13] - v[14];
    w_a  = v[2] + v[3] + v[6] + v[7] - v[8] - v[9] - v[12] - v[13];
    w_b  = v[4] + v[5] + v[6] + v[7] - v[8] - v[9] - v[10] - v[11];
    w_c  = v[8] + v[9] + v[10] + v[11] + v[12] + v[13] + v[14] + v[15];
}

// Kernel 1: per-column softmax -> SoA coefficients + packed u16 index pairs.
__global__ __launch_bounds__(256) void gate_weights_kernel(
    const float* __restrict__ logits,
    const int* __restrict__ a_idx, const int* __restrict__ b_idx,
    float* __restrict__ ws) {
    int j = blockIdx.x * blockDim.x + threadIdx.x;
    if (j >= OUT_DIM) return;
    float w_ab, w_a, w_b, w_c;
    collapse_weights(logits + (size_t)j * NG, w_ab, w_a, w_b, w_c);
    ws[j]               = w_ab;
    ws[j +     OUT_DIM] = w_a;
    ws[j + 2 * OUT_DIM] = w_b;
    ws[j + 3 * OUT_DIM] = w_c;
    unsigned int* pk = (unsigned int*)(ws + 4 * OUT_DIM);
    pk[j] = (unsigned int)a_idx[j] | ((unsigned int)b_idx[j] << 16);
}

// Kernel 2: grid = (BATCH/RROWS)*CHUNKS. Stage RROWS=2 fp32 rows (64 KB LDS),
// then per column: one pk load + 4 SoA weight loads feed BOTH rows' outputs.
__global__ __launch_bounds__(TPB, 4) void gate_eval_kernel(
    const float* __restrict__ x,
    const float* __restrict__ ws,
    f32x4* __restrict__ out4) {
    __shared__ float rows[RROWS * IN_DIM];
    const int bid   = blockIdx.x;
    const int ipair = bid >> 1;          // row-pair index (CHUNKS == 2)
    const int chunk = bid & 1;
    const int i0    = ipair * RROWS;

    const f32x4* xr = (const f32x4*)(x + (size_t)i0 * IN_DIM);
    f32x4* rv = (f32x4*)rows;
#pragma unroll
    for (int t = 0; t < RROWS * IN_DIM / 4 / TPB; ++t)   // 8 iters
        rv[threadIdx.x + t * TPB] = xr[threadIdx.x + t * TPB];
    __syncthreads();

    const f32x4* wab4 = (const f32x4*)(ws);
    const f32x4* wa4  = (const f32x4*)(ws + OUT_DIM);
    const f32x4* wb4  = (const f32x4*)(ws + 2 * OUT_DIM);
    const f32x4* wc4  = (const f32x4*)(ws + 3 * OUT_DIM);
    const u32x4* pk4  = (const u32x4*)(ws + 4 * OUT_DIM);

    const int base4 = chunk * (OUT_DIM / CHUNKS / 4);
    f32x4* o0 = out4 + (size_t)i0 * (OUT_DIM / 4);
    f32x4* o1 = o0 + (OUT_DIM / 4);

#pragma unroll 2
    for (int k = 0; k < OUT_DIM / CHUNKS / 4 / TPB; ++k) {  // 4 iters
        int j4 = base4 + threadIdx.x + k * TPB;
        u32x4 pk = pk4[j4];
        f32x4 wab = wab4[j4], wa = wa4[j4], wb = wb4[j4], wc = wc4[j4];
        f32x4 r0, r1;
#pragma unroll
        for (int c = 0; c < 4; ++c) {
            int ia = (int)(pk[c] & 0xFFFFu);
            int ib = (int)(pk[c] >> 16);
            float a0 = rows[ia],          b0 = rows[ib];
            float a1 = rows[ia + IN_DIM], b1 = rows[ib + IN_DIM];
            r0[c] = fmaf(wab[c], a0 * b0, fmaf(wa[c], a0, fmaf(wb[c], b0, wc[c])));
            r1[c] = fmaf(wab[c], a1 * b1, fmaf(wa[c], a1, fmaf(wb[c], b1, wc[c])));
        }
        __builtin_nontemporal_store(r0, &o0[j4]);
        __builtin_nontemporal_store(r1, &o1[j4]);
    }
}

// Fallback if ws_size is too small: recompute softmax inline per column.
__global__ __launch_bounds__(256) void gate_eval_fused_kernel(
    const float* __restrict__ x,
    const float* __restrict__ logits,
    const int* __restrict__ a_idx,
    const int* __restrict__ b_idx,
    float* __restrict__ out) {
    __shared__ float row[IN_DIM];
    const int i = blockIdx.x;
    const f32x4* xr = (const f32x4*)(x + (size_t)i * IN_DIM);
    f32x4* rv = (f32x4*)row;
#pragma unroll
    for (int t = 0; t < IN_DIM / 4 / 256; ++t)
        rv[threadIdx.x + t * 256] = xr[threadIdx.x + t * 256];
    __syncthreads();
    float* o = out + (size_t)i * OUT_DIM;
    for (int k = 0; k < OUT_DIM / 256; ++k) {
        int j = threadIdx.x + k * 256;
        float w_ab, w_a, w_b, w_c;
        collapse_weights(logits + (size_t)j * NG, w_ab, w_a, w_b, w_c);
        float a = row[a_idx[j]], b = row[b_idx[j]];
        o[j] = fmaf(w_ab, a * b, fmaf(w_a, a, fmaf(w_b, b, w_c)));
    }
}

extern "C" void kernel_launch(void* const* d_in, const int* in_sizes, int n_in,
                              void* d_out, int out_size, void* d_ws, size_t ws_size,
                              hipStream_t stream) {
    const float* x      = (const float*)d_in[0];
    const float* logits = (const float*)d_in[1];
    const int*   a_idx  = (const int*)d_in[2];
    const int*   b_idx  = (const int*)d_in[3];
    float* out = (float*)d_out;

    const size_t ws_need = (size_t)(4 * OUT_DIM) * sizeof(float)
                         + (size_t)OUT_DIM * sizeof(unsigned int);  // 320 KB
    if (ws_size >= ws_need && d_ws != nullptr) {
        float* ws = (float*)d_ws;
        gate_weights_kernel<<<OUT_DIM / 256, 256, 0, stream>>>(
            logits, a_idx, b_idx, ws);
        gate_eval_kernel<<<(BATCH / RROWS) * CHUNKS, TPB, 0, stream>>>(
            x, ws, (f32x4*)out);
    } else {
        gate_eval_fused_kernel<<<BATCH, 256, 0, stream>>>(
            x, logits, a_idx, b_idx, out);
    }
}

// Round 7
// 49.354 us; speedup vs baseline: 1.2175x; 1.0176x over previous
//
#include <hip/hip_runtime.h>
#include <hip/hip_bf16.h>

#define IN_DIM  8192
#define OUT_DIM 16384
#define BATCH   2048
#define NG      16
#define CHUNKS  2     // column-chunks per row-pair
#define RROWS   2     // batch rows per block (table amortization)
#define TPB     512
#define NITER   (OUT_DIM / CHUNKS / 4 / TPB)   // 4

typedef float        f32x4 __attribute__((ext_vector_type(4)));
typedef unsigned int u32x4 __attribute__((ext_vector_type(4)));

// ---------------------------------------------------------------------------
// Gate mixture is linear in {a*b, a, b, 1}: out = w_ab*ab + w_a*a + w_b*b + w_c.
// ws layout (SoA): [w_ab | w_a | w_b | w_c] (4*OUT_DIM f32), then packed
// indices (OUT_DIM u32: a_idx | b_idx<<16).
// Eval: 2 rows/block share table reads; table loads software-pipelined so
// VMEM (L2) latency hides under LDS gathers + FMAs of the previous iter.
// ---------------------------------------------------------------------------

__device__ __forceinline__ void collapse_weights(const float* __restrict__ l,
                                                 float& w_ab, float& w_a,
                                                 float& w_b, float& w_c) {
    float v[NG];
    float m = -1e30f;
#pragma unroll
    for (int k = 0; k < NG; ++k) { v[k] = l[k]; m = fmaxf(m, v[k]); }
    float s = 0.f;
#pragma unroll
    for (int k = 0; k < NG; ++k) { v[k] = __expf(v[k] - m); s += v[k]; }
    float inv = 1.0f / s;
#pragma unroll
    for (int k = 0; k < NG; ++k) v[k] *= inv;
    w_ab = v[1] - v[2] - v[4] - 2.f * v[6] - v[7] + v[8] + 2.f * v[9]
         + v[11] + v[13] - v[14];
    w_a  = v[2] + v[3] + v[6] + v[7] - v[8] - v[9] - v[12] - v[13];
    w_b  = v[4] + v[5] + v[6] + v[7] - v[8] - v[9] - v[10] - v[11];
    w_c  = v[8] + v[9] + v[10] + v[11] + v[12] + v[13] + v[14] + v[15];
}

// Kernel 1: per-column softmax -> SoA coefficients + packed u16 index pairs.
__global__ __launch_bounds__(256) void gate_weights_kernel(
    const float* __restrict__ logits,
    const int* __restrict__ a_idx, const int* __restrict__ b_idx,
    float* __restrict__ ws) {
    int j = blockIdx.x * blockDim.x + threadIdx.x;
    if (j >= OUT_DIM) return;
    float w_ab, w_a, w_b, w_c;
    collapse_weights(logits + (size_t)j * NG, w_ab, w_a, w_b, w_c);
    ws[j]               = w_ab;
    ws[j +     OUT_DIM] = w_a;
    ws[j + 2 * OUT_DIM] = w_b;
    ws[j + 3 * OUT_DIM] = w_c;
    unsigned int* pk = (unsigned int*)(ws + 4 * OUT_DIM);
    pk[j] = (unsigned int)a_idx[j] | ((unsigned int)b_idx[j] << 16);
}

// Kernel 2: grid = (BATCH/RROWS)*CHUNKS. Stage RROWS=2 fp32 rows (64 KB LDS);
// table loads double-buffered: iter k+1's 5 loads in flight during iter k's
// gathers/FMAs; iter 0's loads in flight during staging.
__global__ __launch_bounds__(TPB, 4) void gate_eval_kernel(
    const float* __restrict__ x,
    const float* __restrict__ ws,
    f32x4* __restrict__ out4) {
    __shared__ float rows[RROWS * IN_DIM];
    const int bid   = blockIdx.x;
    const int ipair = bid >> 1;          // row-pair index (CHUNKS == 2)
    const int chunk = bid & 1;
    const int i0    = ipair * RROWS;

    const f32x4* wab4 = (const f32x4*)(ws);
    const f32x4* wa4  = (const f32x4*)(ws + OUT_DIM);
    const f32x4* wb4  = (const f32x4*)(ws + 2 * OUT_DIM);
    const f32x4* wc4  = (const f32x4*)(ws + 3 * OUT_DIM);
    const u32x4* pk4  = (const u32x4*)(ws + 4 * OUT_DIM);
    const int base4 = chunk * (OUT_DIM / CHUNKS / 4);

    // Prefetch iter-0 table BEFORE staging: in flight during the 8 staging loads.
    u32x4 pkb[2];
    f32x4 wabb[2], wab_[2], wbb[2], wcb[2];
    {
        int j4 = base4 + threadIdx.x;
        pkb[0]  = pk4[j4];
        wabb[0] = wab4[j4];
        wab_[0] = wa4[j4];
        wbb[0]  = wb4[j4];
        wcb[0]  = wc4[j4];
    }

    const f32x4* xr = (const f32x4*)(x + (size_t)i0 * IN_DIM);
    f32x4* rv = (f32x4*)rows;
#pragma unroll
    for (int t = 0; t < RROWS * IN_DIM / 4 / TPB; ++t)   // 8 iters
        rv[threadIdx.x + t * TPB] = xr[threadIdx.x + t * TPB];
    __syncthreads();

    f32x4* o0 = out4 + (size_t)i0 * (OUT_DIM / 4);
    f32x4* o1 = o0 + (OUT_DIM / 4);

#pragma unroll
    for (int k = 0; k < NITER; ++k) {                    // 4, fully unrolled
        const int cur = k & 1, nxt = cur ^ 1;
        if (k + 1 < NITER) {                             // prefetch next table
            int j4n = base4 + threadIdx.x + (k + 1) * TPB;
            pkb[nxt]  = pk4[j4n];
            wabb[nxt] = wab4[j4n];
            wab_[nxt] = wa4[j4n];
            wbb[nxt]  = wb4[j4n];
            wcb[nxt]  = wc4[j4n];
        }
        int j4 = base4 + threadIdx.x + k * TPB;
        u32x4 pk = pkb[cur];
        f32x4 wab = wabb[cur], wa = wab_[cur], wb = wbb[cur], wc = wcb[cur];
        f32x4 r0, r1;
#pragma unroll
        for (int c = 0; c < 4; ++c) {
            int ia = (int)(pk[c] & 0xFFFFu);
            int ib = (int)(pk[c] >> 16);
            float a0 = rows[ia],          b0 = rows[ib];
            float a1 = rows[ia + IN_DIM], b1 = rows[ib + IN_DIM];
            r0[c] = fmaf(wab[c], a0 * b0, fmaf(wa[c], a0, fmaf(wb[c], b0, wc[c])));
            r1[c] = fmaf(wab[c], a1 * b1, fmaf(wa[c], a1, fmaf(wb[c], b1, wc[c])));
        }
        __builtin_nontemporal_store(r0, &o0[j4]);
        __builtin_nontemporal_store(r1, &o1[j4]);
    }
}

// Fallback if ws_size is too small: recompute softmax inline per column.
__global__ __launch_bounds__(256) void gate_eval_fused_kernel(
    const float* __restrict__ x,
    const float* __restrict__ logits,
    const int* __restrict__ a_idx,
    const int* __restrict__ b_idx,
    float* __restrict__ out) {
    __shared__ float row[IN_DIM];
    const int i = blockIdx.x;
    const f32x4* xr = (const f32x4*)(x + (size_t)i * IN_DIM);
    f32x4* rv = (f32x4*)row;
#pragma unroll
    for (int t = 0; t < IN_DIM / 4 / 256; ++t)
        rv[threadIdx.x + t * 256] = xr[threadIdx.x + t * 256];
    __syncthreads();
    float* o = out + (size_t)i * OUT_DIM;
    for (int k = 0; k < OUT_DIM / 256; ++k) {
        int j = threadIdx.x + k * 256;
        float w_ab, w_a, w_b, w_c;
        collapse_weights(logits + (size_t)j * NG, w_ab, w_a, w_b, w_c);
        float a = row[a_idx[j]], b = row[b_idx[j]];
        o[j] = fmaf(w_ab, a * b, fmaf(w_a, a, fmaf(w_b, b, w_c)));
    }
}

extern "C" void kernel_launch(void* const* d_in, const int* in_sizes, int n_in,
                              void* d_out, int out_size, void* d_ws, size_t ws_size,
                              hipStream_t stream) {
    const float* x      = (const float*)d_in[0];
    const float* logits = (const float*)d_in[1];
    const int*   a_idx  = (const int*)d_in[2];
    const int*   b_idx  = (const int*)d_in[3];
    float* out = (float*)d_out;

    const size_t ws_need = (size_t)(4 * OUT_DIM) * sizeof(float)
                         + (size_t)OUT_DIM * sizeof(unsigned int);  // 320 KB
    if (ws_size >= ws_need && d_ws != nullptr) {
        float* ws = (float*)d_ws;
        gate_weights_kernel<<<OUT_DIM / 256, 256, 0, stream>>>(
            logits, a_idx, b_idx, ws);
        gate_eval_kernel<<<(BATCH / RROWS) * CHUNKS, TPB, 0, stream>>>(
            x, ws, (f32x4*)out);
    } else {
        gate_eval_fused_kernel<<<BATCH, 256, 0, stream>>>(
            x, logits, a_idx, b_idx, out);
    }
}

// Round 8
// 40.032 us; speedup vs baseline: 1.5010x; 1.2329x over previous
//
#include <hip/hip_runtime.h>
#include <hip/hip_bf16.h>

#define IN_DIM  8192
#define OUT_DIM 16384
#define BATCH   2048
#define NG      16
#define RROWS   2     // batch rows per block, interleaved in LDS
#define TPB     512
#define NITER   (OUT_DIM / 4 / TPB)   // 8

typedef float        f32x2 __attribute__((ext_vector_type(2)));
typedef float        f32x4 __attribute__((ext_vector_type(4)));
typedef unsigned int u32x4 __attribute__((ext_vector_type(4)));

// ---------------------------------------------------------------------------
// Gate mixture is linear in {a*b, a, b, 1}: out = w_ab*ab + w_a*a + w_b*b + w_c.
// ws layout (SoA): [w_ab | w_a | w_b | w_c] (4*OUT_DIM f32), then packed
// indices (OUT_DIM u32: a_idx | b_idx<<16).
// Eval: rows 2i,2i+1 interleaved as float2 in LDS -> ONE ds_read_b64 per
// operand serves both rows. Each row-pair staged exactly once (CHUNKS=1).
// ---------------------------------------------------------------------------

__device__ __forceinline__ void collapse_weights(const float* __restrict__ l,
                                                 float& w_ab, float& w_a,
                                                 float& w_b, float& w_c) {
    float v[NG];
    float m = -1e30f;
#pragma unroll
    for (int k = 0; k < NG; ++k) { v[k] = l[k]; m = fmaxf(m, v[k]); }
    float s = 0.f;
#pragma unroll
    for (int k = 0; k < NG; ++k) { v[k] = __expf(v[k] - m); s += v[k]; }
    float inv = 1.0f / s;
#pragma unroll
    for (int k = 0; k < NG; ++k) v[k] *= inv;
    w_ab = v[1] - v[2] - v[4] - 2.f * v[6] - v[7] + v[8] + 2.f * v[9]
         + v[11] + v[13] - v[14];
    w_a  = v[2] + v[3] + v[6] + v[7] - v[8] - v[9] - v[12] - v[13];
    w_b  = v[4] + v[5] + v[6] + v[7] - v[8] - v[9] - v[10] - v[11];
    w_c  = v[8] + v[9] + v[10] + v[11] + v[12] + v[13] + v[14] + v[15];
}

// Kernel 1: per-column softmax -> SoA coefficients + packed u16 index pairs.
__global__ __launch_bounds__(256) void gate_weights_kernel(
    const float* __restrict__ logits,
    const int* __restrict__ a_idx, const int* __restrict__ b_idx,
    float* __restrict__ ws) {
    int j = blockIdx.x * blockDim.x + threadIdx.x;
    if (j >= OUT_DIM) return;
    float w_ab, w_a, w_b, w_c;
    collapse_weights(logits + (size_t)j * NG, w_ab, w_a, w_b, w_c);
    ws[j]               = w_ab;
    ws[j +     OUT_DIM] = w_a;
    ws[j + 2 * OUT_DIM] = w_b;
    ws[j + 3 * OUT_DIM] = w_c;
    unsigned int* pk = (unsigned int*)(ws + 4 * OUT_DIM);
    pk[j] = (unsigned int)a_idx[j] | ((unsigned int)b_idx[j] << 16);
}

// Kernel 2: grid = BATCH/RROWS. Stage rows {2i,2i+1} interleaved as float2
// (64 KB LDS); per column: 1 pk + 4 weight loads (double-buffered) + 2 b64
// gathers -> 2 outputs; NT f32x4 stores.
__global__ __launch_bounds__(TPB, 4) void gate_eval_kernel(
    const float* __restrict__ x,
    const float* __restrict__ ws,
    f32x4* __restrict__ out4) {
    __shared__ f32x2 rows2[IN_DIM];
    const int i0 = blockIdx.x * RROWS;

    const f32x4* wab4 = (const f32x4*)(ws);
    const f32x4* wa4  = (const f32x4*)(ws + OUT_DIM);
    const f32x4* wb4  = (const f32x4*)(ws + 2 * OUT_DIM);
    const f32x4* wc4  = (const f32x4*)(ws + 3 * OUT_DIM);
    const u32x4* pk4  = (const u32x4*)(ws + 4 * OUT_DIM);

    // Prefetch iter-0 table BEFORE staging (in flight during staging loads).
    u32x4 pkb[2];
    f32x4 wabb[2], wab_[2], wbb[2], wcb[2];
    {
        int j4 = threadIdx.x;
        pkb[0]  = pk4[j4];
        wabb[0] = wab4[j4];
        wab_[0] = wa4[j4];
        wbb[0]  = wb4[j4];
        wcb[0]  = wc4[j4];
    }

    // Stage + interleave: thread handles 4 chunks of 4 consecutive k.
    const f32x4* xr0 = (const f32x4*)(x + (size_t)i0 * IN_DIM);
    const f32x4* xr1 = (const f32x4*)(x + (size_t)(i0 + 1) * IN_DIM);
#pragma unroll
    for (int t = 0; t < IN_DIM / 4 / TPB; ++t) {   // 4 iters
        int m = threadIdx.x + t * TPB;             // f32x4-chunk index
        f32x4 r0 = xr0[m];
        f32x4 r1 = xr1[m];
#pragma unroll
        for (int c = 0; c < 4; ++c) {
            f32x2 p; p.x = r0[c]; p.y = r1[c];
            rows2[m * 4 + c] = p;
        }
    }
    __syncthreads();

    f32x4* o0 = out4 + (size_t)i0 * (OUT_DIM / 4);
    f32x4* o1 = o0 + (OUT_DIM / 4);

#pragma unroll
    for (int k = 0; k < NITER; ++k) {              // 8, fully unrolled
        const int cur = k & 1, nxt = cur ^ 1;
        if (k + 1 < NITER) {                       // prefetch next table
            int j4n = threadIdx.x + (k + 1) * TPB;
            pkb[nxt]  = pk4[j4n];
            wabb[nxt] = wab4[j4n];
            wab_[nxt] = wa4[j4n];
            wbb[nxt]  = wb4[j4n];
            wcb[nxt]  = wc4[j4n];
        }
        int j4 = threadIdx.x + k * TPB;
        u32x4 pk = pkb[cur];
        f32x4 wab = wabb[cur], wa = wab_[cur], wb = wbb[cur], wc = wcb[cur];
        f32x4 r0, r1;
#pragma unroll
        for (int c = 0; c < 4; ++c) {
            f32x2 va = rows2[pk[c] & 0xFFFFu];     // {row0[ia], row1[ia]}
            f32x2 vb = rows2[pk[c] >> 16];         // {row0[ib], row1[ib]}
            r0[c] = fmaf(wab[c], va.x * vb.x,
                         fmaf(wa[c], va.x, fmaf(wb[c], vb.x, wc[c])));
            r1[c] = fmaf(wab[c], va.y * vb.y,
                         fmaf(wa[c], va.y, fmaf(wb[c], vb.y, wc[c])));
        }
        __builtin_nontemporal_store(r0, &o0[j4]);
        __builtin_nontemporal_store(r1, &o1[j4]);
    }
}

// Fallback if ws_size is too small: recompute softmax inline per column.
__global__ __launch_bounds__(256) void gate_eval_fused_kernel(
    const float* __restrict__ x,
    const float* __restrict__ logits,
    const int* __restrict__ a_idx,
    const int* __restrict__ b_idx,
    float* __restrict__ out) {
    __shared__ float row[IN_DIM];
    const int i = blockIdx.x;
    const f32x4* xr = (const f32x4*)(x + (size_t)i * IN_DIM);
    f32x4* rv = (f32x4*)row;
#pragma unroll
    for (int t = 0; t < IN_DIM / 4 / 256; ++t)
        rv[threadIdx.x + t * 256] = xr[threadIdx.x + t * 256];
    __syncthreads();
    float* o = out + (size_t)i * OUT_DIM;
    for (int k = 0; k < OUT_DIM / 256; ++k) {
        int j = threadIdx.x + k * 256;
        float w_ab, w_a, w_b, w_c;
        collapse_weights(logits + (size_t)j * NG, w_ab, w_a, w_b, w_c);
        float a = row[a_idx[j]], b = row[b_idx[j]];
        o[j] = fmaf(w_ab, a * b, fmaf(w_a, a, fmaf(w_b, b, w_c)));
    }
}

extern "C" void kernel_launch(void* const* d_in, const int* in_sizes, int n_in,
                              void* d_out, int out_size, void* d_ws, size_t ws_size,
                              hipStream_t stream) {
    const float* x      = (const float*)d_in[0];
    const float* logits = (const float*)d_in[1];
    const int*   a_idx  = (const int*)d_in[2];
    const int*   b_idx  = (const int*)d_in[3];
    float* out = (float*)d_out;

    const size_t ws_need = (size_t)(4 * OUT_DIM) * sizeof(float)
                         + (size_t)OUT_DIM * sizeof(unsigned int);  // 320 KB
    if (ws_size >= ws_need && d_ws != nullptr) {
        float* ws = (float*)d_ws;
        gate_weights_kernel<<<OUT_DIM / 256, 256, 0, stream>>>(
            logits, a_idx, b_idx, ws);
        gate_eval_kernel<<<BATCH / RROWS, TPB, 0, stream>>>(
            x, ws, (f32x4*)out);
    } else {
        gate_eval_fused_kernel<<<BATCH, 256, 0, stream>>>(
            x, logits, a_idx, b_idx, out);
    }
}